// Round 5
// baseline (283.893 us; speedup 1.0000x reference)
//
#include <hip/hip_runtime.h>
#include <cstddef>
#include <cstdint>

// ---------------------------------------------------------------------------
// MultiHeadSelfAttention: x(4,2048,1024) fp32, W(3072,1024) fp32, Wo(1024,1024)
// Pipeline: cvt->bf16 | GEMM1 qkv | RoPE(Q,K) | transpose V | flash attn | GEMM2
// r15: Guideline-13 vectorization sweep (no structural changes):
//  - gemm_bt: MFMA operands swapped (mfma(b,a)) so lane holds 4 consecutive
//    N-cols -> C stores become uint2(bf16)/uint4(f32), 16 instead of 64 scalar
//    stores, 4-8x coalescing. Bit-identical results (same dots, f2bf RNE).
//  - rope_qk: 16B/thread (4 pairs), one (b,l) row per block, uint4 I/O.
//  - transpose_v: pack-2 LDS transpose (u32 = two l per d), XOR-swizzled u32
//    index (2-way max on ds_write_b32), uint4 global loads AND stores.
// attn unchanged from r14.
// ---------------------------------------------------------------------------

typedef unsigned short u16;
typedef short bf16x8 __attribute__((ext_vector_type(8)));   // 8 bf16 = 4 VGPRs
typedef float f32x4 __attribute__((ext_vector_type(4)));

#define B_   4
#define L_   2048
#define H_   16
#define DH_  64
#define D_   1024
#define E3_  3072

__device__ __forceinline__ u16 f2bf(float f) {            // RNE f32 -> bf16
  unsigned int u = __float_as_uint(f);
  u += 0x7fffu + ((u >> 16) & 1u);
  return (u16)(u >> 16);
}
__device__ __forceinline__ float bf2f(u16 h) {
  return __uint_as_float(((unsigned int)h) << 16);
}
// round-half-up pack of two f32 -> bf16x2 (5 VALU ops)
__device__ __forceinline__ unsigned pk2(float a, float b) {
  return ((__float_as_uint(a) + 0x8000u) >> 16) |
         ((__float_as_uint(b) + 0x8000u) & 0xffff0000u);
}
__device__ __forceinline__ float fexp2(float x) {
#if __has_builtin(__builtin_amdgcn_exp2f)
  return __builtin_amdgcn_exp2f(x);
#else
  return exp2f(x);
#endif
}

// async global->LDS DMA, 16 bytes/lane. LDS dest = wave-uniform base + lane*16
__device__ __forceinline__ void gload_lds16(const void* g, void* l) {
  auto gp = reinterpret_cast<const uint32_t __attribute__((address_space(1)))*>(
      reinterpret_cast<uintptr_t>(g));
  auto lp = reinterpret_cast<uint32_t __attribute__((address_space(3)))*>(
      reinterpret_cast<uintptr_t>(l));
  __builtin_amdgcn_global_load_lds(gp, lp, 16, 0, 0);
}

// ---------------------------------------------------------------- cvt fp32->bf16
__global__ __launch_bounds__(256) void cvt_bf16(const float* __restrict__ in,
                                                u16* __restrict__ out, int n8) {
  int i = blockIdx.x * 256 + threadIdx.x;
  if (i >= n8) return;
  const float4* p = (const float4*)in;
  float4 a = p[2 * i], b = p[2 * i + 1];
  uint4 o;
  o.x = (unsigned)f2bf(a.x) | ((unsigned)f2bf(a.y) << 16);
  o.y = (unsigned)f2bf(a.z) | ((unsigned)f2bf(a.w) << 16);
  o.z = (unsigned)f2bf(b.x) | ((unsigned)f2bf(b.y) << 16);
  o.w = (unsigned)f2bf(b.z) | ((unsigned)f2bf(b.w) << 16);
  ((uint4*)out)[i] = o;
}

// ---------------------------------------------------------------- GEMM C = A * B^T
// 128x128 block tile, 4 waves (2x2 of 64x64), BK=32, m97 structure:
// global_load_lds width=16 into linear [128][32] u16 LDS (64 B rows).
// MFMA operands swapped: lane holds row m = l15, cols n = quad*4+reg ->
// vectorized C stores (uint2 bf16 / uint4 f32).
template <bool OUT_BF16>
__global__ __launch_bounds__(256) void gemm_bt(const u16* __restrict__ A,
                                               const u16* __restrict__ Bm,
                                               void* __restrict__ C, int N, int K) {
  __shared__ __align__(16) u16 As[128 * 32];
  __shared__ __align__(16) u16 Bs[128 * 32];
  const int tid = threadIdx.x;
  const int lane = tid & 63, wave = tid >> 6;
  const int quad = lane >> 4, l15 = lane & 15;
  const int wm = (wave >> 1) << 6, wn = (wave & 1) << 6;
  const int m0 = blockIdx.y << 7, n0 = blockIdx.x << 7;

  f32x4 acc[4][4];
#pragma unroll
  for (int i = 0; i < 4; ++i)
#pragma unroll
    for (int j = 0; j < 4; ++j) acc[i][j] = {0.f, 0.f, 0.f, 0.f};

  const int sr = lane >> 2;           // row within 16-row DMA chunk
  const int sc = (lane & 3) * 8;      // u16 col chunk (16 B)

  for (int k0 = 0; k0 < K; k0 += 32) {
#pragma unroll
    for (int it = 0; it < 2; ++it) {
      const int chunk = wave * 2 + it;          // 0..7 (16 rows each)
      const int row = chunk * 16 + sr;
      gload_lds16(A + (size_t)(m0 + row) * K + k0 + sc, As + chunk * 512);
      gload_lds16(Bm + (size_t)(n0 + row) * K + k0 + sc, Bs + chunk * 512);
    }
    __syncthreads();                  // drains vmcnt(0): LDS tiles complete
    bf16x8 af[4], bfr[4];
#pragma unroll
    for (int i = 0; i < 4; ++i)
      af[i] = *(const bf16x8*)(As + (wm + i * 16 + l15) * 32 + quad * 8);
#pragma unroll
    for (int j = 0; j < 4; ++j)
      bfr[j] = *(const bf16x8*)(Bs + (wn + j * 16 + l15) * 32 + quad * 8);
#pragma unroll
    for (int i = 0; i < 4; ++i)
#pragma unroll
      for (int j = 0; j < 4; ++j)
        acc[i][j] = __builtin_amdgcn_mfma_f32_16x16x32_bf16(bfr[j], af[i],
                                                            acc[i][j], 0, 0, 0);
    __syncthreads();                  // readers done before next DMA overwrites
  }
  // epilogue: swapped product -> lane holds row m = wm+i*16+l15,
  // cols n = wn+j*16+quad*4 + reg (4 consecutive) -> vector stores.
#pragma unroll
  for (int i = 0; i < 4; ++i) {
    const int row = m0 + wm + i * 16 + l15;
#pragma unroll
    for (int j = 0; j < 4; ++j) {
      const int col = n0 + wn + j * 16 + quad * 4;
      if (OUT_BF16) {
        uint2 o = {(unsigned)f2bf(acc[i][j][0]) |
                       ((unsigned)f2bf(acc[i][j][1]) << 16),
                   (unsigned)f2bf(acc[i][j][2]) |
                       ((unsigned)f2bf(acc[i][j][3]) << 16)};
        *(uint2*)((u16*)C + (size_t)row * N + col) = o;
      } else {
        *(f32x4*)((float*)C + (size_t)row * N + col) = acc[i][j];
      }
    }
  }
}

// ---------------------------------------------------------------- RoPE on Q,K (in place, bf16)
// one (b,l) row per block; thread: c=tid&7 (d-chunk), h=(tid>>3)&15, t=tid>>7.
// 16B per thread = 4 rotation pairs (d2 = c*4+j).
__global__ __launch_bounds__(256) void rope_qk(u16* __restrict__ qkvb) {
  const int bl = blockIdx.x;                 // b*L + l
  const int l = bl & (L_ - 1);
  const int tid = threadIdx.x;
  const int c = tid & 7, h = (tid >> 3) & 15, t = tid >> 7;
  u16* p = qkvb + (size_t)bl * E3_ + t * D_ + h * DH_ + c * 8;
  uint4 v = *(const uint4*)p;
  unsigned* w = (unsigned*)&v;
  const float scale = t ? 1.0f : 0.18033688011112042f;
#pragma unroll
  for (int j = 0; j < 4; ++j) {
    const int d2 = c * 4 + j;
    float inv = exp2f((float)d2 * -0.5190512648261504f);
    float ang = (float)l * inv;
    float sn = __sinf(ang), cs = __cosf(ang);
    float x1 = bf2f((u16)(w[j] & 0xffffu)), x2 = bf2f((u16)(w[j] >> 16));
    float o1 = (x1 * cs - x2 * sn) * scale;
    float o2 = (x2 * cs + x1 * sn) * scale;
    w[j] = (unsigned)f2bf(o1) | ((unsigned)f2bf(o2) << 16);
  }
  *(uint4*)p = v;
}

// ---------------------------------------------------------------- V transpose: (b,l,h,d)->(b,h,d,l)
// pack-2 LDS transpose: tile[d][36 u32], u32 = (val(l even), val(l odd)).
// u32 index XOR-swizzled by (d>>3)<<2 -> ds_write_b32 2-way max; reads are
// uint4 (aligned: swizzle stays within the 4-u32 chunk index). uint4 global
// loads and stores on both phases.
__global__ __launch_bounds__(256) void transpose_v(const u16* __restrict__ qkvb,
                                                   u16* __restrict__ Vt) {
  __shared__ uint32_t tile[64 * 36];               // [d][36], 9 uint4 per row
  const int bh = blockIdx.x, b = bh >> 4, h = bh & 15;
  const int lbase = blockIdx.y << 6;
  const int tid = threadIdx.x;
  {  // write phase: 256 units = 32 row-pairs x 8 d-chunks
    const int ur = tid >> 3, c = tid & 7;          // l-pair, d-chunk
    const u16* src = qkvb + (size_t)(b * L_ + lbase + 2 * ur) * E3_ + 2 * D_ +
                     h * DH_ + c * 8;
    uint4 va = *(const uint4*)src;                 // row l = 2*ur
    uint4 vb = *(const uint4*)(src + E3_);         // row l = 2*ur+1
    const unsigned* pa = (const unsigned*)&va;
    const unsigned* pb = (const unsigned*)&vb;
    const int us = ur ^ (c << 2);                  // swizzled u32 slot
#pragma unroll
    for (int q = 0; q < 4; ++q) {
      const int d0 = c * 8 + 2 * q;
      tile[d0 * 36 + us] = (pa[q] & 0xffffu) | (pb[q] << 16);
      tile[(d0 + 1) * 36 + us] = (pa[q] >> 16) | (pb[q] & 0xffff0000u);
    }
  }
  __syncthreads();
  const uint4* t4 = (const uint4*)tile;
#pragma unroll
  for (int it = 0; it < 2; ++it) {                 // 512 units = 64 d x 8 lc
    const int u = it * 256 + tid;
    const int d = u >> 3, lc = u & 7;
    uint4 v = t4[d * 9 + (lc ^ (d >> 3))];
    *(uint4*)(Vt + (size_t)(bh * DH_ + d) * L_ + lbase + lc * 8) = v;
  }
}

// ---------------------------------------------------------------- flash attention (causal)
// grid (8 pairs, B*H), 8 waves x 512 threads; block (p,bh) runs 128-row
// q-tile 15-p then p (uniform 34 k-iters). Wave owns 16 q-rows (1 m-tile).
// Transposed MFMA dataflow: S^T=mfma(kf,qf), O^T=mfma(vf,pf), l=mfma(ones,pf).
// K/V: unpadded [64][64] dbuf LDS, staged via global_load_lds (wave w stages
// rows w*8..w*8+7; lane l -> row w*8+(l>>3), 16B granule l&7, source granule
// pre-swizzled (l&7)^(l>>3)). Reads use granule G^(row&7). One barrier/iter.
__global__ __launch_bounds__(512) void attn(const u16* __restrict__ qkvb,
                                            const u16* __restrict__ Vt,
                                            u16* __restrict__ Ob) {
  __shared__ __align__(16) u16 Ks[2][64 * 64];     // [dbuf][key][d], XOR-swz
  __shared__ __align__(16) u16 Vs[2][64 * 64];     // [dbuf][d][key], XOR-swz
  __shared__ __align__(16) u16 Ps[8][16 * 72];     // per-wave P / O tile [q][.]
  const int bh = blockIdx.y, b = bh >> 4, h = bh & 15;
  const int pair = blockIdx.x;                     // 0..7
  const int tid = threadIdx.x;
  const int lane = tid & 63, wave = tid >> 6, quad = lane >> 4, l15 = lane & 15;
  u16* pw = Ps[wave];

  // DMA staging: wave w covers rows w*8..w*8+7 of the 64-row tile.
  const int srow = wave * 8 + (lane >> 3);          // row this lane sources
  const int sgran = (lane & 7) ^ (lane >> 3);       // pre-swizzled 16B granule
  const u16* ksrc0 =
      qkvb + (size_t)(b * L_ + srow) * E3_ + D_ + h * DH_ + sgran * 8;
  const u16* vsrc0 = Vt + (size_t)(bh * DH_ + srow) * L_ + sgran * 8;
  const int ldst = wave * 512;                      // per-wave uniform LDS dest

  bf16x8 ones;
#pragma unroll
  for (int i = 0; i < 8; ++i) ones[i] = (short)0x3F80;   // bf16 1.0

  for (int a = 0; a < 2; ++a) {
    const int qbase = (a ? pair : (15 - pair)) << 7;   // long tile first
    const int rb = qbase + wave * 16;                  // wave's q-row base
    const int qg = rb + l15;                           // this lane's q row

    // Q fragments (layout [q=l15][k=quad*8+j])
    bf16x8 qf[2];
    {
      const u16* qp = qkvb + (size_t)(b * L_ + qg) * E3_ + h * DH_;
      qf[0] = *(const bf16x8*)(qp + quad * 8);
      qf[1] = *(const bf16x8*)(qp + 32 + quad * 8);
    }

    f32x4 acc[4], lacc;                // O^T tile + l (col q=l15)
    lacc = {0.f, 0.f, 0.f, 0.f};
#pragma unroll
    for (int j = 0; j < 4; ++j) acc[j] = {0.f, 0.f, 0.f, 0.f};

    // prologue: DMA k-tile 0 into buf 0
    gload_lds16(ksrc0, Ks[0] + ldst);
    gload_lds16(vsrc0, Vs[0] + ldst);
    __syncthreads();                   // drain DMA (vmcnt 0) + rendezvous

    const int kend = qbase + 128;
    int cur = 0;
    for (int kb = 0; kb < kend; kb += 64, cur ^= 1) {
      // issue DMA for next tile into the idle buffer (free since the barrier
      // at the end of iter kb-64 separated its last readers)
      if (kb + 64 < kend) {
        gload_lds16(ksrc0 + (size_t)(kb + 64) * E3_, Ks[cur ^ 1] + ldst);
        gload_lds16(vsrc0 + (kb + 64), Vs[cur ^ 1] + ldst);
      }
      const u16* kcur = Ks[cur];
      const u16* vcur = Vs[cur];

      // S^T = mfma(kf, qf): lane holds col q=l15, rows key=t*16+quad*4+r
      f32x4 st[4];
#pragma unroll
      for (int t = 0; t < 4; ++t) st[t] = {0.f, 0.f, 0.f, 0.f};
      __builtin_amdgcn_s_setprio(1);
#pragma unroll
      for (int ks = 0; ks < 2; ++ks) {
        bf16x8 kf[4];
#pragma unroll
        for (int t = 0; t < 4; ++t)
          kf[t] = *(const bf16x8*)(kcur + (t * 16 + l15) * 64 +
                                   (((ks * 4 + quad) ^ (l15 & 7)) * 8));
#pragma unroll
        for (int t = 0; t < 4; ++t)
          st[t] = __builtin_amdgcn_mfma_f32_16x16x32_bf16(kf[t], qf[ks],
                                                          st[t], 0, 0, 0);
      }
      __builtin_amdgcn_s_setprio(0);

      // p = exp2(s) (masked -> 0), packed b64 store to P[q][key]
      {
        const bool dg = (kb + 63 > rb);          // diagonal overlap
#pragma unroll
        for (int t = 0; t < 4; ++t) {
          const int kg0 = kb + t * 16 + quad * 4;
          float p0, p1, p2, p3;
          if (dg) {
            p0 = (kg0 + 0 > qg) ? 0.f : fexp2(st[t][0]);
            p1 = (kg0 + 1 > qg) ? 0.f : fexp2(st[t][1]);
            p2 = (kg0 + 2 > qg) ? 0.f : fexp2(st[t][2]);
            p3 = (kg0 + 3 > qg) ? 0.f : fexp2(st[t][3]);
          } else {
            p0 = fexp2(st[t][0]);
            p1 = fexp2(st[t][1]);
            p2 = fexp2(st[t][2]);
            p3 = fexp2(st[t][3]);
          }
          uint2 pkd = {pk2(p0, p1), pk2(p2, p3)};
          *(uint2*)(pw + l15 * 72 + t * 16 + quad * 4) = pkd;
        }
      }
      // same-wave LDS write -> read ordering without draining the DMA (vmcnt)
      asm volatile("s_waitcnt lgkmcnt(0)" ::: "memory");
      __builtin_amdgcn_sched_barrier(0);

      // O^T += mfma(vf, pf) ; l += mfma(ones, pf)
      __builtin_amdgcn_s_setprio(1);
#pragma unroll
      for (int ks = 0; ks < 2; ++ks) {
        bf16x8 vf[4];
#pragma unroll
        for (int j = 0; j < 4; ++j)
          vf[j] = *(const bf16x8*)(vcur + (j * 16 + l15) * 64 +
                                   (((ks * 4 + quad) ^ (l15 & 7)) * 8));
        bf16x8 pf = *(const bf16x8*)(pw + l15 * 72 + ks * 32 + quad * 8);
        lacc = __builtin_amdgcn_mfma_f32_16x16x32_bf16(ones, pf, lacc,
                                                       0, 0, 0);
#pragma unroll
        for (int j = 0; j < 4; ++j)
          acc[j] = __builtin_amdgcn_mfma_f32_16x16x32_bf16(vf[j], pf,
                                                           acc[j], 0, 0, 0);
      }
      __builtin_amdgcn_s_setprio(0);

      __syncthreads();   // buf[cur] readers done; buf[cur^1] DMA complete
    }

    // epilogue: O^T lane holds col q=l15, rows d=j*16+quad*4+r; lacc uniform
    // across regs -> one reciprocal per wave; packed b64 stores to [q][d].
    {
      const float rl = 1.0f / lacc[0];
#pragma unroll
      for (int j = 0; j < 4; ++j) {
        uint2 od = {pk2(acc[j][0] * rl, acc[j][1] * rl),
                    pk2(acc[j][2] * rl, acc[j][3] * rl)};
        *(uint2*)(pw + l15 * 72 + j * 16 + quad * 4) = od;
      }
    }
    __syncthreads();   // all waves' O tiles staged
#pragma unroll
    for (int it = 0; it < 2; ++it) {
      int unit = it * 512 + tid;                 // 1024 units = 128 rows x 8
      int row = unit >> 3, ch = (unit & 7) * 8;
      *(uint4*)(Ob + (size_t)(b * L_ + qbase + row) * D_ + h * DH_ + ch) =
          *(const uint4*)(Ps[row >> 4] + (row & 15) * 72 + ch);
    }
    __syncthreads();   // store reads done before next tile overwrites Ps
  }
}

// ---------------------------------------------------------------- launch
extern "C" void kernel_launch(void* const* d_in, const int* in_sizes, int n_in,
                              void* d_out, int out_size, void* d_ws, size_t ws_size,
                              hipStream_t stream) {
  const float* x  = (const float*)d_in[0];
  const float* W  = (const float*)d_in[1];
  const float* Wo = (const float*)d_in[2];
  float* out = (float*)d_out;

  char* ws = (char*)d_ws;
  u16* xb   = (u16*)(ws);                    // 16,777,216
  u16* Wb   = (u16*)(ws + 16777216);         //  6,291,456
  u16* Wob  = (u16*)(ws + 23068672);         //  2,097,152
  u16* qkvb = (u16*)(ws + 25165824);         // 50,331,648  (B,L,3,H,DH) bf16
  u16* Vt   = (u16*)(ws + 75497472);         // 16,777,216  (B,H,DH,L) bf16
  u16* Ob   = (u16*)(ws + 92274688);         // 16,777,216  (B,L,D) bf16

  cvt_bf16<<<4096, 256, 0, stream>>>(x, xb, 1048576);
  cvt_bf16<<<1536, 256, 0, stream>>>(W, Wb, 393216);
  cvt_bf16<<<512, 256, 0, stream>>>(Wo, Wob, 131072);

  gemm_bt<true><<<dim3(E3_ / 128, (B_ * L_) / 128), 256, 0, stream>>>(
      xb, Wb, qkvb, E3_, D_);

  rope_qk<<<B_ * L_, 256, 0, stream>>>(qkvb);
  transpose_v<<<dim3(B_ * H_, L_ / 64), 256, 0, stream>>>(qkvb, Vt);

  attn<<<dim3(8, B_ * H_), 512, 0, stream>>>(qkvb, Vt, Ob);

  gemm_bt<false><<<dim3(D_ / 128, (B_ * L_) / 128), 256, 0, stream>>>(
      Ob, Wob, out, D_, D_);
}

// Round 6
// 265.317 us; speedup vs baseline: 1.0700x; 1.0700x over previous
//
#include <hip/hip_runtime.h>
#include <cstddef>
#include <cstdint>

// ---------------------------------------------------------------------------
// MultiHeadSelfAttention: x(4,2048,1024) fp32, W(3072,1024) fp32, Wo(1024,1024)
// Pipeline: cvt->bf16 | GEMM1 qkv (+fused RoPE) | transpose V | flash attn | GEMM2
// r16: (a) REVERT r15's gemm operand swap (measured regression: 79.7->89.3us,
// MfmaUtil 27->24; mechanism unproven, data says revert). Restored r14 main
// loop mfma(af,bfr) + scalar C stores. (b) rope_qk DELETED: rotation fused
// into GEMM1 epilogue. Partner value (col^1) lives in lane^1 -> one
// __shfl_xor; t = n0>>10 is block-uniform (128-aligned tiles); Q scale
// applied at t==0. One fewer bf16 rounding on Q/K. rope/transpose keep r15
// vectorized forms. attn unchanged from r14.
// ---------------------------------------------------------------------------

typedef unsigned short u16;
typedef short bf16x8 __attribute__((ext_vector_type(8)));   // 8 bf16 = 4 VGPRs
typedef float f32x4 __attribute__((ext_vector_type(4)));

#define B_   4
#define L_   2048
#define H_   16
#define DH_  64
#define D_   1024
#define E3_  3072

__device__ __forceinline__ u16 f2bf(float f) {            // RNE f32 -> bf16
  unsigned int u = __float_as_uint(f);
  u += 0x7fffu + ((u >> 16) & 1u);
  return (u16)(u >> 16);
}
__device__ __forceinline__ float bf2f(u16 h) {
  return __uint_as_float(((unsigned int)h) << 16);
}
// round-half-up pack of two f32 -> bf16x2 (5 VALU ops)
__device__ __forceinline__ unsigned pk2(float a, float b) {
  return ((__float_as_uint(a) + 0x8000u) >> 16) |
         ((__float_as_uint(b) + 0x8000u) & 0xffff0000u);
}
__device__ __forceinline__ float fexp2(float x) {
#if __has_builtin(__builtin_amdgcn_exp2f)
  return __builtin_amdgcn_exp2f(x);
#else
  return exp2f(x);
#endif
}

// async global->LDS DMA, 16 bytes/lane. LDS dest = wave-uniform base + lane*16
__device__ __forceinline__ void gload_lds16(const void* g, void* l) {
  auto gp = reinterpret_cast<const uint32_t __attribute__((address_space(1)))*>(
      reinterpret_cast<uintptr_t>(g));
  auto lp = reinterpret_cast<uint32_t __attribute__((address_space(3)))*>(
      reinterpret_cast<uintptr_t>(l));
  __builtin_amdgcn_global_load_lds(gp, lp, 16, 0, 0);
}

// ---------------------------------------------------------------- cvt fp32->bf16
__global__ __launch_bounds__(256) void cvt_bf16(const float* __restrict__ in,
                                                u16* __restrict__ out, int n8) {
  int i = blockIdx.x * 256 + threadIdx.x;
  if (i >= n8) return;
  const float4* p = (const float4*)in;
  float4 a = p[2 * i], b = p[2 * i + 1];
  uint4 o;
  o.x = (unsigned)f2bf(a.x) | ((unsigned)f2bf(a.y) << 16);
  o.y = (unsigned)f2bf(a.z) | ((unsigned)f2bf(a.w) << 16);
  o.z = (unsigned)f2bf(b.x) | ((unsigned)f2bf(b.y) << 16);
  o.w = (unsigned)f2bf(b.z) | ((unsigned)f2bf(b.w) << 16);
  ((uint4*)out)[i] = o;
}

// ---------------------------------------------------------------- GEMM C = A * B^T
// 128x128 block tile, 4 waves (2x2 of 64x64), BK=32, m97 structure:
// global_load_lds width=16 into linear [128][32] u16 LDS (64 B rows).
// r14 epilogue layout: lane holds col = n0+wn+j*16+l15, rows quad*4+r.
// FUSE_ROPE (GEMM1 only): rotate (col even, col odd) pairs via __shfl_xor
// lane^1; d2=(col&63)>>1, ang=l*theta^-(d2/32); Q (t==0) scaled by
// 1/sqrt(DH)*log2e for the exp2-based softmax.
template <bool OUT_BF16, bool FUSE_ROPE>
__global__ __launch_bounds__(256) void gemm_bt(const u16* __restrict__ A,
                                               const u16* __restrict__ Bm,
                                               void* __restrict__ C, int N, int K) {
  __shared__ __align__(16) u16 As[128 * 32];
  __shared__ __align__(16) u16 Bs[128 * 32];
  const int tid = threadIdx.x;
  const int lane = tid & 63, wave = tid >> 6;
  const int quad = lane >> 4, l15 = lane & 15;
  const int wm = (wave >> 1) << 6, wn = (wave & 1) << 6;
  const int m0 = blockIdx.y << 7, n0 = blockIdx.x << 7;

  f32x4 acc[4][4];
#pragma unroll
  for (int i = 0; i < 4; ++i)
#pragma unroll
    for (int j = 0; j < 4; ++j) acc[i][j] = {0.f, 0.f, 0.f, 0.f};

  const int sr = lane >> 2;           // row within 16-row DMA chunk
  const int sc = (lane & 3) * 8;      // u16 col chunk (16 B)

  for (int k0 = 0; k0 < K; k0 += 32) {
#pragma unroll
    for (int it = 0; it < 2; ++it) {
      const int chunk = wave * 2 + it;          // 0..7 (16 rows each)
      const int row = chunk * 16 + sr;
      gload_lds16(A + (size_t)(m0 + row) * K + k0 + sc, As + chunk * 512);
      gload_lds16(Bm + (size_t)(n0 + row) * K + k0 + sc, Bs + chunk * 512);
    }
    __syncthreads();                  // drains vmcnt(0): LDS tiles complete
    bf16x8 af[4], bfr[4];
#pragma unroll
    for (int i = 0; i < 4; ++i)
      af[i] = *(const bf16x8*)(As + (wm + i * 16 + l15) * 32 + quad * 8);
#pragma unroll
    for (int j = 0; j < 4; ++j)
      bfr[j] = *(const bf16x8*)(Bs + (wn + j * 16 + l15) * 32 + quad * 8);
#pragma unroll
    for (int i = 0; i < 4; ++i)
#pragma unroll
      for (int j = 0; j < 4; ++j)
        acc[i][j] = __builtin_amdgcn_mfma_f32_16x16x32_bf16(af[i], bfr[j],
                                                            acc[i][j], 0, 0, 0);
    __syncthreads();                  // readers done before next DMA overwrites
  }

  const int t = n0 >> 10;             // GEMM1: 0=Q, 1=K, 2=V (block-uniform)
#pragma unroll
  for (int i = 0; i < 4; ++i) {
    const int row = m0 + wm + i * 16 + quad * 4;
#pragma unroll
    for (int j = 0; j < 4; ++j) {
      const int col = n0 + wn + j * 16 + l15;
      if (FUSE_ROPE && t < 2) {
        const int d2 = (col & 63) >> 1;
        const float inv = exp2f((float)d2 * -0.5190512648261504f);
        const float qs = (t == 0) ? 0.18033688011112042f : 1.0f;
        const bool odd = col & 1;
#pragma unroll
        for (int r = 0; r < 4; ++r) {
          const int l = (row + r) & (L_ - 1);
          const float ang = (float)l * inv;
          const float sn = __sinf(ang), cs = __cosf(ang);
          const float v = acc[i][j][r];
          const float p = __shfl_xor(v, 1, 64);   // partner col^1 (lane^1)
          const float o = (odd ? (v * cs + p * sn) : (v * cs - p * sn)) * qs;
          ((u16*)C)[(size_t)(row + r) * N + col] = f2bf(o);
        }
      } else {
#pragma unroll
        for (int r = 0; r < 4; ++r) {
          if (OUT_BF16)
            ((u16*)C)[(size_t)(row + r) * N + col] = f2bf(acc[i][j][r]);
          else
            ((float*)C)[(size_t)(row + r) * N + col] = acc[i][j][r];
        }
      }
    }
  }
}

// ---------------------------------------------------------------- V transpose: (b,l,h,d)->(b,h,d,l)
// pack-2 LDS transpose: tile[d][36 u32], u32 = (val(l even), val(l odd)).
// u32 index XOR-swizzled by (d>>3)<<2 -> ds_write_b32 2-way max; reads are
// uint4 (aligned: swizzle stays within the 4-u32 chunk index). uint4 global
// loads and stores on both phases.
__global__ __launch_bounds__(256) void transpose_v(const u16* __restrict__ qkvb,
                                                   u16* __restrict__ Vt) {
  __shared__ uint32_t tile[64 * 36];               // [d][36], 9 uint4 per row
  const int bh = blockIdx.x, b = bh >> 4, h = bh & 15;
  const int lbase = blockIdx.y << 6;
  const int tid = threadIdx.x;
  {  // write phase: 256 units = 32 row-pairs x 8 d-chunks
    const int ur = tid >> 3, c = tid & 7;          // l-pair, d-chunk
    const u16* src = qkvb + (size_t)(b * L_ + lbase + 2 * ur) * E3_ + 2 * D_ +
                     h * DH_ + c * 8;
    uint4 va = *(const uint4*)src;                 // row l = 2*ur
    uint4 vb = *(const uint4*)(src + E3_);         // row l = 2*ur+1
    const unsigned* pa = (const unsigned*)&va;
    const unsigned* pb = (const unsigned*)&vb;
    const int us = ur ^ (c << 2);                  // swizzled u32 slot
#pragma unroll
    for (int q = 0; q < 4; ++q) {
      const int d0 = c * 8 + 2 * q;
      tile[d0 * 36 + us] = (pa[q] & 0xffffu) | (pb[q] << 16);
      tile[(d0 + 1) * 36 + us] = (pa[q] >> 16) | (pb[q] & 0xffff0000u);
    }
  }
  __syncthreads();
  const uint4* t4 = (const uint4*)tile;
#pragma unroll
  for (int it = 0; it < 2; ++it) {                 // 512 units = 64 d x 8 lc
    const int u = it * 256 + tid;
    const int d = u >> 3, lc = u & 7;
    uint4 v = t4[d * 9 + (lc ^ (d >> 3))];
    *(uint4*)(Vt + (size_t)(bh * DH_ + d) * L_ + lbase + lc * 8) = v;
  }
}

// ---------------------------------------------------------------- flash attention (causal)
// grid (8 pairs, B*H), 8 waves x 512 threads; block (p,bh) runs 128-row
// q-tile 15-p then p (uniform 34 k-iters). Wave owns 16 q-rows (1 m-tile).
// Transposed MFMA dataflow: S^T=mfma(kf,qf), O^T=mfma(vf,pf), l=mfma(ones,pf).
// K/V: unpadded [64][64] dbuf LDS, staged via global_load_lds (wave w stages
// rows w*8..w*8+7; lane l -> row w*8+(l>>3), 16B granule l&7, source granule
// pre-swizzled (l&7)^(l>>3)). Reads use granule G^(row&7). One barrier/iter.
__global__ __launch_bounds__(512) void attn(const u16* __restrict__ qkvb,
                                            const u16* __restrict__ Vt,
                                            u16* __restrict__ Ob) {
  __shared__ __align__(16) u16 Ks[2][64 * 64];     // [dbuf][key][d], XOR-swz
  __shared__ __align__(16) u16 Vs[2][64 * 64];     // [dbuf][d][key], XOR-swz
  __shared__ __align__(16) u16 Ps[8][16 * 72];     // per-wave P / O tile [q][.]
  const int bh = blockIdx.y, b = bh >> 4, h = bh & 15;
  const int pair = blockIdx.x;                     // 0..7
  const int tid = threadIdx.x;
  const int lane = tid & 63, wave = tid >> 6, quad = lane >> 4, l15 = lane & 15;
  u16* pw = Ps[wave];

  // DMA staging: wave w covers rows w*8..w*8+7 of the 64-row tile.
  const int srow = wave * 8 + (lane >> 3);          // row this lane sources
  const int sgran = (lane & 7) ^ (lane >> 3);       // pre-swizzled 16B granule
  const u16* ksrc0 =
      qkvb + (size_t)(b * L_ + srow) * E3_ + D_ + h * DH_ + sgran * 8;
  const u16* vsrc0 = Vt + (size_t)(bh * DH_ + srow) * L_ + sgran * 8;
  const int ldst = wave * 512;                      // per-wave uniform LDS dest

  bf16x8 ones;
#pragma unroll
  for (int i = 0; i < 8; ++i) ones[i] = (short)0x3F80;   // bf16 1.0

  for (int a = 0; a < 2; ++a) {
    const int qbase = (a ? pair : (15 - pair)) << 7;   // long tile first
    const int rb = qbase + wave * 16;                  // wave's q-row base
    const int qg = rb + l15;                           // this lane's q row

    // Q fragments (layout [q=l15][k=quad*8+j])
    bf16x8 qf[2];
    {
      const u16* qp = qkvb + (size_t)(b * L_ + qg) * E3_ + h * DH_;
      qf[0] = *(const bf16x8*)(qp + quad * 8);
      qf[1] = *(const bf16x8*)(qp + 32 + quad * 8);
    }

    f32x4 acc[4], lacc;                // O^T tile + l (col q=l15)
    lacc = {0.f, 0.f, 0.f, 0.f};
#pragma unroll
    for (int j = 0; j < 4; ++j) acc[j] = {0.f, 0.f, 0.f, 0.f};

    // prologue: DMA k-tile 0 into buf 0
    gload_lds16(ksrc0, Ks[0] + ldst);
    gload_lds16(vsrc0, Vs[0] + ldst);
    __syncthreads();                   // drain DMA (vmcnt 0) + rendezvous

    const int kend = qbase + 128;
    int cur = 0;
    for (int kb = 0; kb < kend; kb += 64, cur ^= 1) {
      // issue DMA for next tile into the idle buffer (free since the barrier
      // at the end of iter kb-64 separated its last readers)
      if (kb + 64 < kend) {
        gload_lds16(ksrc0 + (size_t)(kb + 64) * E3_, Ks[cur ^ 1] + ldst);
        gload_lds16(vsrc0 + (kb + 64), Vs[cur ^ 1] + ldst);
      }
      const u16* kcur = Ks[cur];
      const u16* vcur = Vs[cur];

      // S^T = mfma(kf, qf): lane holds col q=l15, rows key=t*16+quad*4+r
      f32x4 st[4];
#pragma unroll
      for (int t = 0; t < 4; ++t) st[t] = {0.f, 0.f, 0.f, 0.f};
      __builtin_amdgcn_s_setprio(1);
#pragma unroll
      for (int ks = 0; ks < 2; ++ks) {
        bf16x8 kf[4];
#pragma unroll
        for (int t = 0; t < 4; ++t)
          kf[t] = *(const bf16x8*)(kcur + (t * 16 + l15) * 64 +
                                   (((ks * 4 + quad) ^ (l15 & 7)) * 8));
#pragma unroll
        for (int t = 0; t < 4; ++t)
          st[t] = __builtin_amdgcn_mfma_f32_16x16x32_bf16(kf[t], qf[ks],
                                                          st[t], 0, 0, 0);
      }
      __builtin_amdgcn_s_setprio(0);

      // p = exp2(s) (masked -> 0), packed b64 store to P[q][key]
      {
        const bool dg = (kb + 63 > rb);          // diagonal overlap
#pragma unroll
        for (int t = 0; t < 4; ++t) {
          const int kg0 = kb + t * 16 + quad * 4;
          float p0, p1, p2, p3;
          if (dg) {
            p0 = (kg0 + 0 > qg) ? 0.f : fexp2(st[t][0]);
            p1 = (kg0 + 1 > qg) ? 0.f : fexp2(st[t][1]);
            p2 = (kg0 + 2 > qg) ? 0.f : fexp2(st[t][2]);
            p3 = (kg0 + 3 > qg) ? 0.f : fexp2(st[t][3]);
          } else {
            p0 = fexp2(st[t][0]);
            p1 = fexp2(st[t][1]);
            p2 = fexp2(st[t][2]);
            p3 = fexp2(st[t][3]);
          }
          uint2 pkd = {pk2(p0, p1), pk2(p2, p3)};
          *(uint2*)(pw + l15 * 72 + t * 16 + quad * 4) = pkd;
        }
      }
      // same-wave LDS write -> read ordering without draining the DMA (vmcnt)
      asm volatile("s_waitcnt lgkmcnt(0)" ::: "memory");
      __builtin_amdgcn_sched_barrier(0);

      // O^T += mfma(vf, pf) ; l += mfma(ones, pf)
      __builtin_amdgcn_s_setprio(1);
#pragma unroll
      for (int ks = 0; ks < 2; ++ks) {
        bf16x8 vf[4];
#pragma unroll
        for (int j = 0; j < 4; ++j)
          vf[j] = *(const bf16x8*)(vcur + (j * 16 + l15) * 64 +
                                   (((ks * 4 + quad) ^ (l15 & 7)) * 8));
        bf16x8 pf = *(const bf16x8*)(pw + l15 * 72 + ks * 32 + quad * 8);
        lacc = __builtin_amdgcn_mfma_f32_16x16x32_bf16(ones, pf, lacc,
                                                       0, 0, 0);
#pragma unroll
        for (int j = 0; j < 4; ++j)
          acc[j] = __builtin_amdgcn_mfma_f32_16x16x32_bf16(vf[j], pf,
                                                           acc[j], 0, 0, 0);
      }
      __builtin_amdgcn_s_setprio(0);

      __syncthreads();   // buf[cur] readers done; buf[cur^1] DMA complete
    }

    // epilogue: O^T lane holds col q=l15, rows d=j*16+quad*4+r; lacc uniform
    // across regs -> one reciprocal per wave; packed b64 stores to [q][d].
    {
      const float rl = 1.0f / lacc[0];
#pragma unroll
      for (int j = 0; j < 4; ++j) {
        uint2 od = {pk2(acc[j][0] * rl, acc[j][1] * rl),
                    pk2(acc[j][2] * rl, acc[j][3] * rl)};
        *(uint2*)(pw + l15 * 72 + j * 16 + quad * 4) = od;
      }
    }
    __syncthreads();   // all waves' O tiles staged
#pragma unroll
    for (int it = 0; it < 2; ++it) {
      int unit = it * 512 + tid;                 // 1024 units = 128 rows x 8
      int row = unit >> 3, ch = (unit & 7) * 8;
      *(uint4*)(Ob + (size_t)(b * L_ + qbase + row) * D_ + h * DH_ + ch) =
          *(const uint4*)(Ps[row >> 4] + (row & 15) * 72 + ch);
    }
    __syncthreads();   // store reads done before next tile overwrites Ps
  }
}

// ---------------------------------------------------------------- launch
extern "C" void kernel_launch(void* const* d_in, const int* in_sizes, int n_in,
                              void* d_out, int out_size, void* d_ws, size_t ws_size,
                              hipStream_t stream) {
  const float* x  = (const float*)d_in[0];
  const float* W  = (const float*)d_in[1];
  const float* Wo = (const float*)d_in[2];
  float* out = (float*)d_out;

  char* ws = (char*)d_ws;
  u16* xb   = (u16*)(ws);                    // 16,777,216
  u16* Wb   = (u16*)(ws + 16777216);         //  6,291,456
  u16* Wob  = (u16*)(ws + 23068672);         //  2,097,152
  u16* qkvb = (u16*)(ws + 25165824);         // 50,331,648  (B,L,3,H,DH) bf16
  u16* Vt   = (u16*)(ws + 75497472);         // 16,777,216  (B,H,DH,L) bf16
  u16* Ob   = (u16*)(ws + 92274688);         // 16,777,216  (B,L,D) bf16

  cvt_bf16<<<4096, 256, 0, stream>>>(x, xb, 1048576);
  cvt_bf16<<<1536, 256, 0, stream>>>(W, Wb, 393216);
  cvt_bf16<<<512, 256, 0, stream>>>(Wo, Wob, 131072);

  gemm_bt<true, true><<<dim3(E3_ / 128, (B_ * L_) / 128), 256, 0, stream>>>(
      xb, Wb, qkvb, E3_, D_);

  transpose_v<<<dim3(B_ * H_, L_ / 64), 256, 0, stream>>>(qkvb, Vt);

  attn<<<dim3(8, B_ * H_), 512, 0, stream>>>(qkvb, Vt, Ob);

  gemm_bt<false, false><<<dim3(D_ / 128, (B_ * L_) / 128), 256, 0, stream>>>(
      Ob, Wob, out, D_, D_);
}